// Round 11
// baseline (466.152 us; speedup 1.0000x reference)
//
#include <hip/hip_runtime.h>
#include <hip/hip_cooperative_groups.h>
#include <cmath>
#include <cstdint>

#pragma clang fp contract(off)

namespace cg = cooperative_groups;

#define B_ 2
#define N_ 65536
#define M_ 128
#define K_ 2048
#define S_ 6
#define NBLK 256          /* classify/compact blocks per batch */
#define CT 256            /* classify/compact threads per block */
#define FPS_T 512         /* 8 waves: 2 waves/SIMD */
#define NW 8              /* FPS_T / 64 waves */
#define RMAX 8            /* per-thread point slots */
#define CAP (FPS_T * RMAX)  /* 4096 points max for register fast path */

#define PI_F 3.14159265358979323846f
#define SS_F 1.0471975511965976f   /* (float)(2.0*pi/6) */

// Wave-wide max of 64-bit keys via DPP (VALU latency, not DS latency).
// Lane 63 holds the result. Identity: key==0 (bound_ctrl zero-fill loses).
__device__ __forceinline__ unsigned long long wave_max_u64_dpp(unsigned long long key) {
#define DPP_STEP(CTRL)                                                          \
    {                                                                           \
        unsigned lo = (unsigned)key, hi = (unsigned)(key >> 32);                \
        unsigned olo = (unsigned)__builtin_amdgcn_update_dpp(0, (int)lo, CTRL, 0xf, 0xf, true); \
        unsigned ohi = (unsigned)__builtin_amdgcn_update_dpp(0, (int)hi, CTRL, 0xf, 0xf, true); \
        unsigned long long o = ((unsigned long long)ohi << 32) | olo;           \
        if (o > key) key = o;                                                   \
    }
    DPP_STEP(0x111)  /* row_shr:1  */
    DPP_STEP(0x112)  /* row_shr:2  */
    DPP_STEP(0x114)  /* row_shr:4  */
    DPP_STEP(0x118)  /* row_shr:8  */
    DPP_STEP(0x142)  /* row_bcast:15 */
    DPP_STEP(0x143)  /* row_bcast:31 */
#undef DPP_STEP
    return key;
}

// ----------------------------------------- pre: classify + plan + compact ----
// Single cooperative kernel. Phase 1 = old k_classify body; grid.sync()
// (blkcnt is the ONLY cross-block data); Phase 2 = old k_compact(+plan)
// body. Because phase-1 block i and phase-2 block i cover the same gid
// range, sec and the point xyz stay in REGISTERS across the sync — the
// 512KB sec_id global round-trip is gone. Saves one launch gap (~17-22us
// measured per launch in r8->r9).
__global__ __launch_bounds__(CT)
void k_pre(const float* __restrict__ points, const float* __restrict__ rois,
           int* __restrict__ blkcnt,
           int* __restrict__ cnt, int* __restrict__ offv,
           int* __restrict__ n_needed, int* __restrict__ sec_base_g,
           int* __restrict__ s_total,
           int* __restrict__ comp_idx, float4* __restrict__ comp_xyz,
           int* __restrict__ done_ctr) {
    __shared__ float4 sroi[M_];
    __shared__ int lc8[8];
    __shared__ int scnt_lds[NBLK][8];        // 8KB: batch-b blkcnt mirror
    __shared__ int sbase[6], blkb[6], stot[8];
    __shared__ int lc[4 * 6];

    int blk = blockIdx.x;
    int tid = threadIdx.x, lane = tid & 63, wid = tid >> 6;
    int gid = blk * CT + tid;
    int b = gid >> 16;                       // == blk >> 8
    int j = blk & 255;                       // block index within batch

    if (blk == 0 && tid == 0) *done_ctr = 0; // reset fps+out fusion ctr
    if (tid < M_) {
        const float* r = rois + ((size_t)b * M_ + tid) * 7;
        float cz = r[2] + r[5] * 0.5f;       // geometric center
        float hx = r[3] * 0.5f, hy = r[4] * 0.5f, hz = r[5] * 0.5f;
        sroi[tid] = make_float4(r[0], r[1], cz, sqrtf((hx*hx + hy*hy) + hz*hz));
    }
    if (tid < 8) lc8[tid] = 0;
    __syncthreads();

    const float* p = points + (size_t)gid * 3;
    float px = p[0], py = p[1], pz = p[2];
    float best = 1e30f; int bi = 0;
    for (int m = 0; m < M_; m++) {
        float4 c = sroi[m];
        float dx = px - c.x, dy = py - c.y, dz = pz - c.z;
        float d = sqrtf((dx*dx + dy*dy) + dz*dz);
        if (d < best) { best = d; bi = m; }  // strict < : first argmin
    }
    bool valid = best < (sroi[bi].w + 1.6f);

    float a = atan2f(py, px) + PI_F;
    float fs = floorf(a / SS_F);
    fs = fminf(fmaxf(fs, 0.0f), 6.0f);
    int sec = valid ? (int)fs : -1;          // kept in register for phase 2

    if (valid) atomicAdd(&lc8[(int)fs], 1);
    __syncthreads();
    if (tid < 8) blkcnt[blk * 8 + tid] = lc8[tid];

    // ---- grid-wide sync: all blkcnt writes visible (device fence first) ----
    __threadfence();
    cg::this_grid().sync();

    // ---- phase 2: compact (+inline plan), sec/xyz still in registers ----
    {   // stage batch-b blkcnt: 256 threads x one 32B row
        const int4* src = (const int4*)(blkcnt + (size_t)(b * NBLK + tid) * 8);
        int4 r0 = src[0], r1 = src[1];
        *(int4*)&scnt_lds[tid][0] = r0;
        *(int4*)&scnt_lds[tid][4] = r1;
    }
    __syncthreads();
    if (tid < 7) {                            // per-sector prefix + total
        int run = 0, pref = 0;
        for (int j2 = 0; j2 < NBLK; j2++) {
            if (j2 == j) pref = run;
            run += scnt_lds[j2][tid];
        }
        stot[tid] = run;
        if (tid < 6) blkb[tid] = pref;
    }
    __syncthreads();
    if (tid == 0) {                           // sector bases from totals
        int sb = 0;
        for (int s = 0; s < 6; s++) { sbase[s] = sb; sb += stot[s]; }
    }
    if (j == 0 && tid == 64) {                // plan outputs (original formulas)
        int total = 0;
        for (int s = 0; s < 7; s++) total += stot[s];
        if (total < 1) total = 1;
        int sb = 0, snk = 0;
        for (int s = 0; s < 6; s++) {
            int cs = stot[s];
            int nk = (int)ceilf((float)cs * 2048.0f / (float)total);  // f32 semantics
            if (nk > cs) nk = cs;
            offv[b * 6 + s] = snk;
            int need = 0;
            if (snk < K_) { need = K_ - snk; if (need > nk) need = nk; }
            n_needed[b * 6 + s] = need;
            sec_base_g[b * 6 + s] = sb;
            cnt[b * 8 + s] = cs;
            sb += cs; snk += nk;
        }
        s_total[b] = (snk < 1) ? 1 : snk;
    }

    unsigned long long mymask = 0;
    for (int s = 0; s < 6; s++) {
        unsigned long long m = __ballot(sec == s);
        if (sec == s) mymask = m;
        if (lane == 0) lc[wid * 6 + s] = __popcll(m);
    }
    __syncthreads();
    if (sec >= 0 && sec < 6) {
        int woff = 0;
        for (int w = 0; w < wid; w++) woff += lc[w * 6 + sec];
        int rank = __popcll(mymask & ((1ull << lane) - 1ull));
        int addr = b * N_ + sbase[sec] + blkb[sec] + woff + rank;
        comp_idx[addr] = gid & (N_ - 1);
        comp_xyz[addr] = make_float4(px, py, pz, 0.0f);   // register-held xyz
    }
}

// ------------------------------------------------------ fps (+inline out) ----
// one block (512 thr, 8 waves = 2/SIMD) per (b,s). Pick loop is the EXACT
// round-3 text (the only config measured at 322us / 68 VGPR; r10 re-verified
// 326.8us / 68 VGPR with the fused tail). r7/r8/r9 post-mortem: every
// "instruction-count optimization" of this loop dropped VGPR 68->52 and
// REGRESSED 15-30% at equal VALU-cycles. DO NOT TOUCH THE LOOP BODY.
// Fused k_out tail (verified r9/r10): release = threadfence + atomicAdd
// after writeback; last arriver gathers out[]. All blocks reach the counter.
__global__ __launch_bounds__(FPS_T, 2)
void k_fps(const int* __restrict__ cnt, const int* __restrict__ sec_base,
           const int* __restrict__ offv, const int* __restrict__ n_needed,
           const float4* __restrict__ comp_xyz,
           float* __restrict__ dmin_g, int* __restrict__ buf,
           const float* __restrict__ points, const int* __restrict__ comp_idx,
           const int* __restrict__ s_total, float* __restrict__ out,
           int* __restrict__ done_ctr) {
    __shared__ float4 sxyz[CAP];
    __shared__ int pick_lds[K_];
    __shared__ unsigned long long skey[2][NW];
    __shared__ int is_last;
    int b = blockIdx.x / S_, s = blockIdx.x % S_;
    int need = n_needed[b * 6 + s];
    int cs = cnt[b * 8 + s];
    int base = b * N_ + sec_base[b * 6 + s];
    const float4* cxyz = comp_xyz + base;
    int off = b * K_ + offv[b * 6 + s];
    int tid = threadIdx.x, lane = tid & 63, wid = tid >> 6;

    if (need > 0 && cs <= CAP) {
        // ---- fast path: points + dmin in registers, xyz mirror in LDS ----
        float px[RMAX], py[RMAX], pz[RMAX], dmv[RMAX];
        #pragma unroll
        for (int r = 0; r < RMAX; r++) {
            if (r * FPS_T < cs) {
                int i = tid + r * FPS_T;
                if (i < cs) {
                    float4 q = cxyz[i];
                    sxyz[i] = q;
                    px[r] = q.x; py[r] = q.y; pz[r] = q.z;
                    dmv[r] = 1e10f;
                }
            }
        }
        if (tid == 0) pick_lds[0] = 0;       // first pick = first point
        __syncthreads();
        float4 l4 = sxyz[0];
        float lx = l4.x, ly = l4.y, lz = l4.z;

        #pragma unroll 1
        for (int k = 1; k < need; k++) {
            unsigned long long t[4] = {0ull, 0ull, 0ull, 0ull};
            #pragma unroll
            for (int r = 0; r < RMAX; r++) {
                if (r * FPS_T < cs) {        // wave-uniform
                    int i = tid + r * FPS_T;
                    if (i < cs) {
                        float dx = px[r] - lx, dy = py[r] - ly, dz = pz[r] - lz;
                        float d = (dx*dx + dy*dy) + dz*dz;    // contract off
                        float nd = fminf(dmv[r], d);
                        dmv[r] = nd;
                        unsigned long long kk =
                            ((unsigned long long)__float_as_uint(nd) << 32) | (unsigned)(~(unsigned)i);
                        if (kk > t[r & 3]) t[r & 3] = kk;     // 4 parallel chains
                    }
                }
            }
            unsigned long long ta = (t[1] > t[0]) ? t[1] : t[0];
            unsigned long long tb = (t[3] > t[2]) ? t[3] : t[2];
            unsigned long long key = (tb > ta) ? tb : ta;
            key = wave_max_u64_dpp(key);
            int par = k & 1;
            if (lane == 63) skey[par][wid] = key;
            __syncthreads();
            unsigned long long q0 = skey[par][0], q1 = skey[par][1];
            unsigned long long q2 = skey[par][2], q3 = skey[par][3];
            unsigned long long q4 = skey[par][4], q5 = skey[par][5];
            unsigned long long q6 = skey[par][6], q7 = skey[par][7];
            q0 = (q1 > q0) ? q1 : q0;
            q2 = (q3 > q2) ? q3 : q2;
            q4 = (q5 > q4) ? q5 : q4;
            q6 = (q7 > q6) ? q7 : q6;
            q0 = (q2 > q0) ? q2 : q0;
            q4 = (q6 > q4) ? q6 : q4;
            unsigned long long bk = (q4 > q0) ? q4 : q0;
            int bix = (int)(~(unsigned)(bk & 0xFFFFFFFFull));
            if (tid == 0) pick_lds[k] = bix;                  // LDS, not global
            float4 n4 = sxyz[bix];                            // LDS broadcast
            lx = n4.x; ly = n4.y; lz = n4.z;
        }
        __syncthreads();
        // coalesced writeback of all picks
        #pragma unroll 1
        for (int i = tid; i < need; i += FPS_T)
            buf[off + i] = base + pick_lds[i];
    } else if (need > 0) {
        // ---- fallback: dmin in global (not taken for this data: cs<=CAP) ----
        float* dm = dmin_g + base;
        if (tid == 0) pick_lds[0] = 0;
        __syncthreads();
        float4 f0 = cxyz[0];
        float lx = f0.x, ly = f0.y, lz = f0.z;
        #pragma unroll 1
        for (int k = 1; k < need; k++) {
            unsigned long long key = 0;
            #pragma unroll 1
            for (int i = tid; i < cs; i += FPS_T) {
                float4 q = cxyz[i];
                float dx = q.x - lx, dy = q.y - ly, dz = q.z - lz;
                float d = (dx*dx + dy*dy) + dz*dz;
                float prev = (k == 1) ? 1e10f : dm[i];
                float nd = fminf(prev, d);
                dm[i] = nd;
                unsigned long long kk =
                    ((unsigned long long)__float_as_uint(nd) << 32) | (unsigned)(~(unsigned)i);
                if (kk > key) key = kk;
            }
            key = wave_max_u64_dpp(key);
            int par = k & 1;
            if (lane == 63) skey[par][wid] = key;
            __syncthreads();
            unsigned long long q0 = skey[par][0], q1 = skey[par][1];
            unsigned long long q2 = skey[par][2], q3 = skey[par][3];
            unsigned long long q4 = skey[par][4], q5 = skey[par][5];
            unsigned long long q6 = skey[par][6], q7 = skey[par][7];
            q0 = (q1 > q0) ? q1 : q0;
            q2 = (q3 > q2) ? q3 : q2;
            q4 = (q5 > q4) ? q5 : q4;
            q6 = (q7 > q6) ? q7 : q6;
            q0 = (q2 > q0) ? q2 : q0;
            q4 = (q6 > q4) ? q6 : q4;
            unsigned long long bk = (q4 > q0) ? q4 : q0;
            int bix = (int)(~(unsigned)(bk & 0xFFFFFFFFull));
            if (tid == 0) pick_lds[k] = bix;
            float4 n4 = cxyz[bix];                            // rare path
            lx = n4.x; ly = n4.y; lz = n4.z;
        }
        __syncthreads();
        #pragma unroll 1
        for (int i = tid; i < need; i += FPS_T)
            buf[off + i] = base + pick_lds[i];
    }

    // ---- last-block inline k_out (all 12 blocks arrive here) ----
    __syncthreads();                          // writeback done (block-local)
    if (tid == 0) {
        __threadfence();                      // release buf writes
        int old = atomicAdd(done_ctr, 1);     // device-scope
        is_last = (old == B_ * S_ - 1) ? 1 : 0;
    }
    __syncthreads();
    if (is_last) {
        __threadfence();                      // acquire other blocks' buf
        #pragma unroll 1
        for (int i = tid; i < B_ * K_; i += FPS_T) {
            int b2 = i / K_, j2 = i - b2 * K_;
            int st = s_total[b2];
            int g = buf[b2 * K_ + (j2 % st)]; // compacted global slot
            int idx = comp_idx[g];            // original point index
            const float* p = points + ((size_t)b2 * N_ + idx) * 3;
            float* o = out + (size_t)i * 3;
            o[0] = p[0]; o[1] = p[1]; o[2] = p[2];
        }
    }
}

// -------------------------------------------------------------- launch ----
extern "C" void kernel_launch(void* const* d_in, const int* in_sizes, int n_in,
                              void* d_out, int out_size, void* d_ws, size_t ws_size,
                              hipStream_t stream) {
    const float* points = (const float*)d_in[0];   // [B,N,3]
    const float* rois   = (const float*)d_in[1];   // [B,M,7]
    float* out = (float*)d_out;                    // [B,K,3]

    char* w = (char*)d_ws;
    auto carve = [&](size_t bytes) -> char* {
        char* p = w; w += (bytes + 255) & ~(size_t)255; return p;
    };
    int*    blkcnt   = (int*)   carve((size_t)B_ * NBLK * 8 * sizeof(int));
    int*    cnt      = (int*)   carve((size_t)B_ * 8 * sizeof(int));
    int*    offv     = (int*)   carve((size_t)B_ * 6 * sizeof(int));
    int*    n_needed = (int*)   carve((size_t)B_ * 6 * sizeof(int));
    int*    sec_base = (int*)   carve((size_t)B_ * 6 * sizeof(int));
    int*    s_total  = (int*)   carve((size_t)B_ * sizeof(int));
    int*    buf      = (int*)   carve((size_t)B_ * K_ * sizeof(int));
    int*    comp_idx = (int*)   carve((size_t)B_ * N_ * sizeof(int));
    float4* comp_xyz = (float4*)carve((size_t)B_ * N_ * sizeof(float4));
    float*  dmin_g   = (float*) carve((size_t)B_ * N_ * sizeof(float));
    int*    done_ctr = (int*)   carve(sizeof(int));

    {
        void* args[] = { (void*)&points, (void*)&rois, (void*)&blkcnt,
                         (void*)&cnt, (void*)&offv, (void*)&n_needed,
                         (void*)&sec_base, (void*)&s_total,
                         (void*)&comp_idx, (void*)&comp_xyz, (void*)&done_ctr };
        hipLaunchCooperativeKernel((const void*)k_pre, dim3(B_ * NBLK), dim3(CT),
                                   args, 0, stream);
    }
    hipLaunchKernelGGL(k_fps, dim3(B_ * S_), dim3(FPS_T), 0, stream,
                       cnt, sec_base, offv, n_needed, comp_xyz, dmin_g, buf,
                       points, comp_idx, s_total, out, done_ctr);
}

// Round 12
// 441.590 us; speedup vs baseline: 1.0556x; 1.0556x over previous
//
#include <hip/hip_runtime.h>
#include <cmath>
#include <cstdint>

#pragma clang fp contract(off)

#define B_ 2
#define N_ 65536
#define M_ 128
#define K_ 2048
#define S_ 6
#define NBLK 256          /* classify/compact blocks per batch */
#define CT 256            /* classify/compact threads per block */
#define FPS_T 512         /* 8 waves: 2 waves/SIMD */
#define NW 8              /* FPS_T / 64 waves */
#define RMAX 8            /* per-thread point slots */
#define CAP (FPS_T * RMAX)  /* 4096 points max for register fast path */

#define PI_F 3.14159265358979323846f
#define SS_F 1.0471975511965976f   /* (float)(2.0*pi/6) */

// Wave-wide max of 64-bit keys via DPP (VALU latency, not DS latency).
// Lane 63 holds the result. Identity: key==0 (bound_ctrl zero-fill loses).
__device__ __forceinline__ unsigned long long wave_max_u64_dpp(unsigned long long key) {
#define DPP_STEP(CTRL)                                                          \
    {                                                                           \
        unsigned lo = (unsigned)key, hi = (unsigned)(key >> 32);                \
        unsigned olo = (unsigned)__builtin_amdgcn_update_dpp(0, (int)lo, CTRL, 0xf, 0xf, true); \
        unsigned ohi = (unsigned)__builtin_amdgcn_update_dpp(0, (int)hi, CTRL, 0xf, 0xf, true); \
        unsigned long long o = ((unsigned long long)ohi << 32) | olo;           \
        if (o > key) key = o;                                                   \
    }
    DPP_STEP(0x111)  /* row_shr:1  */
    DPP_STEP(0x112)  /* row_shr:2  */
    DPP_STEP(0x114)  /* row_shr:4  */
    DPP_STEP(0x118)  /* row_shr:8  */
    DPP_STEP(0x142)  /* row_bcast:15 */
    DPP_STEP(0x143)  /* row_bcast:31 */
#undef DPP_STEP
    return key;
}

// ----------------------------------------- pre: classify + plan + compact ----
// Single REGULAR-launch kernel (r11's cooperative version verified correct,
// but hipLaunchCooperativeKernel cost ~+90us of launch overhead). Grid sync
// replaced by a software barrier: writers fence -> block barrier -> tid0
// atomicAdd + spin until all 512 blocks arrive -> fence -> block barrier.
// Deadlock-safe by capacity: 512 blocks x 256 thr @ ~10.3KB LDS = 2
// blocks/CU x 256 CUs — ALL blocks co-resident by construction. The
// cross-block visibility pattern (fence + device atomic + fence) is the
// same one verified absmax=0 in the r9/r10 fps->out fusion. Counters are
// zeroed by hipMemsetAsync on the stream before launch (capture-legal).
// sec + xyz stay in REGISTERS across the barrier (no sec_id round-trip).
__global__ __launch_bounds__(CT)
void k_pre(const float* __restrict__ points, const float* __restrict__ rois,
           int* __restrict__ blkcnt,
           int* __restrict__ cnt, int* __restrict__ offv,
           int* __restrict__ n_needed, int* __restrict__ sec_base_g,
           int* __restrict__ s_total,
           int* __restrict__ comp_idx, float4* __restrict__ comp_xyz,
           int* __restrict__ bar_ctr) {
    __shared__ float4 sroi[M_];
    __shared__ int lc8[8];
    __shared__ int scnt_lds[NBLK][8];        // 8KB: batch-b blkcnt mirror
    __shared__ int sbase[6], blkb[6], stot[8];
    __shared__ int lc[4 * 6];

    int blk = blockIdx.x;
    int tid = threadIdx.x, lane = tid & 63, wid = tid >> 6;
    int gid = blk * CT + tid;
    int b = gid >> 16;                       // == blk >> 8
    int j = blk & 255;                       // block index within batch

    if (tid < M_) {
        const float* r = rois + ((size_t)b * M_ + tid) * 7;
        float cz = r[2] + r[5] * 0.5f;       // geometric center
        float hx = r[3] * 0.5f, hy = r[4] * 0.5f, hz = r[5] * 0.5f;
        sroi[tid] = make_float4(r[0], r[1], cz, sqrtf((hx*hx + hy*hy) + hz*hz));
    }
    if (tid < 8) lc8[tid] = 0;
    __syncthreads();

    const float* p = points + (size_t)gid * 3;
    float px = p[0], py = p[1], pz = p[2];
    float best = 1e30f; int bi = 0;
    for (int m = 0; m < M_; m++) {
        float4 c = sroi[m];
        float dx = px - c.x, dy = py - c.y, dz = pz - c.z;
        float d = sqrtf((dx*dx + dy*dy) + dz*dz);
        if (d < best) { best = d; bi = m; }  // strict < : first argmin
    }
    bool valid = best < (sroi[bi].w + 1.6f);

    float a = atan2f(py, px) + PI_F;
    float fs = floorf(a / SS_F);
    fs = fminf(fmaxf(fs, 0.0f), 6.0f);
    int sec = valid ? (int)fs : -1;          // kept in register for phase 2

    if (valid) atomicAdd(&lc8[(int)fs], 1);
    __syncthreads();
    if (tid < 8) blkcnt[blk * 8 + tid] = lc8[tid];

    // ---- software grid barrier (all 512 blocks co-resident) ----
    __threadfence();                          // release blkcnt stores
    __syncthreads();                          // all threads' fences done
    if (tid == 0) {
        atomicAdd(bar_ctr, 1);                // device-scope arrival
        while (((volatile int*)bar_ctr)[0] < B_ * NBLK) {}
        __threadfence();                      // acquire other blocks' blkcnt
    }
    __syncthreads();                          // release block into phase 2

    // ---- phase 2: compact (+inline plan), sec/xyz still in registers ----
    {   // stage batch-b blkcnt: 256 threads x one 32B row
        const int4* src = (const int4*)(blkcnt + (size_t)(b * NBLK + tid) * 8);
        int4 r0 = src[0], r1 = src[1];
        *(int4*)&scnt_lds[tid][0] = r0;
        *(int4*)&scnt_lds[tid][4] = r1;
    }
    __syncthreads();
    if (tid < 7) {                            // per-sector prefix + total
        int run = 0, pref = 0;
        for (int j2 = 0; j2 < NBLK; j2++) {
            if (j2 == j) pref = run;
            run += scnt_lds[j2][tid];
        }
        stot[tid] = run;
        if (tid < 6) blkb[tid] = pref;
    }
    __syncthreads();
    if (tid == 0) {                           // sector bases from totals
        int sb = 0;
        for (int s = 0; s < 6; s++) { sbase[s] = sb; sb += stot[s]; }
    }
    if (j == 0 && tid == 64) {                // plan outputs (original formulas)
        int total = 0;
        for (int s = 0; s < 7; s++) total += stot[s];
        if (total < 1) total = 1;
        int sb = 0, snk = 0;
        for (int s = 0; s < 6; s++) {
            int cs = stot[s];
            int nk = (int)ceilf((float)cs * 2048.0f / (float)total);  // f32 semantics
            if (nk > cs) nk = cs;
            offv[b * 6 + s] = snk;
            int need = 0;
            if (snk < K_) { need = K_ - snk; if (need > nk) need = nk; }
            n_needed[b * 6 + s] = need;
            sec_base_g[b * 6 + s] = sb;
            cnt[b * 8 + s] = cs;
            sb += cs; snk += nk;
        }
        s_total[b] = (snk < 1) ? 1 : snk;
    }

    unsigned long long mymask = 0;
    for (int s = 0; s < 6; s++) {
        unsigned long long m = __ballot(sec == s);
        if (sec == s) mymask = m;
        if (lane == 0) lc[wid * 6 + s] = __popcll(m);
    }
    __syncthreads();
    if (sec >= 0 && sec < 6) {
        int woff = 0;
        for (int w = 0; w < wid; w++) woff += lc[w * 6 + sec];
        int rank = __popcll(mymask & ((1ull << lane) - 1ull));
        int addr = b * N_ + sbase[sec] + blkb[sec] + woff + rank;
        comp_idx[addr] = gid & (N_ - 1);
        comp_xyz[addr] = make_float4(px, py, pz, 0.0f);   // register-held xyz
    }
}

// ------------------------------------------------------ fps (+inline out) ----
// one block (512 thr, 8 waves = 2/SIMD) per (b,s). Pick loop is the EXACT
// round-3 text (verified 322us r3 / 326.8us r10/r11 at 68 VGPR). r7/r8/r9
// post-mortem: every "instruction-count optimization" of this loop dropped
// VGPR 68->52 and REGRESSED 15-30% at equal VALU-cycles. DO NOT TOUCH.
// Fused k_out tail (verified r9/r10/r11): release = threadfence + atomicAdd
// after writeback; last arriver gathers out[]. All blocks reach the counter.
__global__ __launch_bounds__(FPS_T, 2)
void k_fps(const int* __restrict__ cnt, const int* __restrict__ sec_base,
           const int* __restrict__ offv, const int* __restrict__ n_needed,
           const float4* __restrict__ comp_xyz,
           float* __restrict__ dmin_g, int* __restrict__ buf,
           const float* __restrict__ points, const int* __restrict__ comp_idx,
           const int* __restrict__ s_total, float* __restrict__ out,
           int* __restrict__ done_ctr) {
    __shared__ float4 sxyz[CAP];
    __shared__ int pick_lds[K_];
    __shared__ unsigned long long skey[2][NW];
    __shared__ int is_last;
    int b = blockIdx.x / S_, s = blockIdx.x % S_;
    int need = n_needed[b * 6 + s];
    int cs = cnt[b * 8 + s];
    int base = b * N_ + sec_base[b * 6 + s];
    const float4* cxyz = comp_xyz + base;
    int off = b * K_ + offv[b * 6 + s];
    int tid = threadIdx.x, lane = tid & 63, wid = tid >> 6;

    if (need > 0 && cs <= CAP) {
        // ---- fast path: points + dmin in registers, xyz mirror in LDS ----
        float px[RMAX], py[RMAX], pz[RMAX], dmv[RMAX];
        #pragma unroll
        for (int r = 0; r < RMAX; r++) {
            if (r * FPS_T < cs) {
                int i = tid + r * FPS_T;
                if (i < cs) {
                    float4 q = cxyz[i];
                    sxyz[i] = q;
                    px[r] = q.x; py[r] = q.y; pz[r] = q.z;
                    dmv[r] = 1e10f;
                }
            }
        }
        if (tid == 0) pick_lds[0] = 0;       // first pick = first point
        __syncthreads();
        float4 l4 = sxyz[0];
        float lx = l4.x, ly = l4.y, lz = l4.z;

        #pragma unroll 1
        for (int k = 1; k < need; k++) {
            unsigned long long t[4] = {0ull, 0ull, 0ull, 0ull};
            #pragma unroll
            for (int r = 0; r < RMAX; r++) {
                if (r * FPS_T < cs) {        // wave-uniform
                    int i = tid + r * FPS_T;
                    if (i < cs) {
                        float dx = px[r] - lx, dy = py[r] - ly, dz = pz[r] - lz;
                        float d = (dx*dx + dy*dy) + dz*dz;    // contract off
                        float nd = fminf(dmv[r], d);
                        dmv[r] = nd;
                        unsigned long long kk =
                            ((unsigned long long)__float_as_uint(nd) << 32) | (unsigned)(~(unsigned)i);
                        if (kk > t[r & 3]) t[r & 3] = kk;     // 4 parallel chains
                    }
                }
            }
            unsigned long long ta = (t[1] > t[0]) ? t[1] : t[0];
            unsigned long long tb = (t[3] > t[2]) ? t[3] : t[2];
            unsigned long long key = (tb > ta) ? tb : ta;
            key = wave_max_u64_dpp(key);
            int par = k & 1;
            if (lane == 63) skey[par][wid] = key;
            __syncthreads();
            unsigned long long q0 = skey[par][0], q1 = skey[par][1];
            unsigned long long q2 = skey[par][2], q3 = skey[par][3];
            unsigned long long q4 = skey[par][4], q5 = skey[par][5];
            unsigned long long q6 = skey[par][6], q7 = skey[par][7];
            q0 = (q1 > q0) ? q1 : q0;
            q2 = (q3 > q2) ? q3 : q2;
            q4 = (q5 > q4) ? q5 : q4;
            q6 = (q7 > q6) ? q7 : q6;
            q0 = (q2 > q0) ? q2 : q0;
            q4 = (q6 > q4) ? q6 : q4;
            unsigned long long bk = (q4 > q0) ? q4 : q0;
            int bix = (int)(~(unsigned)(bk & 0xFFFFFFFFull));
            if (tid == 0) pick_lds[k] = bix;                  // LDS, not global
            float4 n4 = sxyz[bix];                            // LDS broadcast
            lx = n4.x; ly = n4.y; lz = n4.z;
        }
        __syncthreads();
        // coalesced writeback of all picks
        #pragma unroll 1
        for (int i = tid; i < need; i += FPS_T)
            buf[off + i] = base + pick_lds[i];
    } else if (need > 0) {
        // ---- fallback: dmin in global (not taken for this data: cs<=CAP) ----
        float* dm = dmin_g + base;
        if (tid == 0) pick_lds[0] = 0;
        __syncthreads();
        float4 f0 = cxyz[0];
        float lx = f0.x, ly = f0.y, lz = f0.z;
        #pragma unroll 1
        for (int k = 1; k < need; k++) {
            unsigned long long key = 0;
            #pragma unroll 1
            for (int i = tid; i < cs; i += FPS_T) {
                float4 q = cxyz[i];
                float dx = q.x - lx, dy = q.y - ly, dz = q.z - lz;
                float d = (dx*dx + dy*dy) + dz*dz;
                float prev = (k == 1) ? 1e10f : dm[i];
                float nd = fminf(prev, d);
                dm[i] = nd;
                unsigned long long kk =
                    ((unsigned long long)__float_as_uint(nd) << 32) | (unsigned)(~(unsigned)i);
                if (kk > key) key = kk;
            }
            key = wave_max_u64_dpp(key);
            int par = k & 1;
            if (lane == 63) skey[par][wid] = key;
            __syncthreads();
            unsigned long long q0 = skey[par][0], q1 = skey[par][1];
            unsigned long long q2 = skey[par][2], q3 = skey[par][3];
            unsigned long long q4 = skey[par][4], q5 = skey[par][5];
            unsigned long long q6 = skey[par][6], q7 = skey[par][7];
            q0 = (q1 > q0) ? q1 : q0;
            q2 = (q3 > q2) ? q3 : q2;
            q4 = (q5 > q4) ? q5 : q4;
            q6 = (q7 > q6) ? q7 : q6;
            q0 = (q2 > q0) ? q2 : q0;
            q4 = (q6 > q4) ? q6 : q4;
            unsigned long long bk = (q4 > q0) ? q4 : q0;
            int bix = (int)(~(unsigned)(bk & 0xFFFFFFFFull));
            if (tid == 0) pick_lds[k] = bix;
            float4 n4 = cxyz[bix];                            // rare path
            lx = n4.x; ly = n4.y; lz = n4.z;
        }
        __syncthreads();
        #pragma unroll 1
        for (int i = tid; i < need; i += FPS_T)
            buf[off + i] = base + pick_lds[i];
    }

    // ---- last-block inline k_out (all 12 blocks arrive here) ----
    __syncthreads();                          // writeback done (block-local)
    if (tid == 0) {
        __threadfence();                      // release buf writes
        int old = atomicAdd(done_ctr, 1);     // device-scope
        is_last = (old == B_ * S_ - 1) ? 1 : 0;
    }
    __syncthreads();
    if (is_last) {
        __threadfence();                      // acquire other blocks' buf
        #pragma unroll 1
        for (int i = tid; i < B_ * K_; i += FPS_T) {
            int b2 = i / K_, j2 = i - b2 * K_;
            int st = s_total[b2];
            int g = buf[b2 * K_ + (j2 % st)]; // compacted global slot
            int idx = comp_idx[g];            // original point index
            const float* p = points + ((size_t)b2 * N_ + idx) * 3;
            float* o = out + (size_t)i * 3;
            o[0] = p[0]; o[1] = p[1]; o[2] = p[2];
        }
    }
}

// -------------------------------------------------------------- launch ----
extern "C" void kernel_launch(void* const* d_in, const int* in_sizes, int n_in,
                              void* d_out, int out_size, void* d_ws, size_t ws_size,
                              hipStream_t stream) {
    const float* points = (const float*)d_in[0];   // [B,N,3]
    const float* rois   = (const float*)d_in[1];   // [B,M,7]
    float* out = (float*)d_out;                    // [B,K,3]

    char* w = (char*)d_ws;
    auto carve = [&](size_t bytes) -> char* {
        char* p = w; w += (bytes + 255) & ~(size_t)255; return p;
    };
    int*    blkcnt   = (int*)   carve((size_t)B_ * NBLK * 8 * sizeof(int));
    int*    cnt      = (int*)   carve((size_t)B_ * 8 * sizeof(int));
    int*    offv     = (int*)   carve((size_t)B_ * 6 * sizeof(int));
    int*    n_needed = (int*)   carve((size_t)B_ * 6 * sizeof(int));
    int*    sec_base = (int*)   carve((size_t)B_ * 6 * sizeof(int));
    int*    s_total  = (int*)   carve((size_t)B_ * sizeof(int));
    int*    buf      = (int*)   carve((size_t)B_ * K_ * sizeof(int));
    int*    comp_idx = (int*)   carve((size_t)B_ * N_ * sizeof(int));
    float4* comp_xyz = (float4*)carve((size_t)B_ * N_ * sizeof(float4));
    float*  dmin_g   = (float*) carve((size_t)B_ * N_ * sizeof(float));
    int*    sync_ctr = (int*)   carve(2 * sizeof(int));   // [0]=bar, [1]=done

    hipMemsetAsync(sync_ctr, 0, 2 * sizeof(int), stream); // capture-legal

    hipLaunchKernelGGL(k_pre, dim3(B_ * NBLK), dim3(CT), 0, stream,
                       points, rois, blkcnt, cnt, offv, n_needed, sec_base,
                       s_total, comp_idx, comp_xyz, &sync_ctr[0]);
    hipLaunchKernelGGL(k_fps, dim3(B_ * S_), dim3(FPS_T), 0, stream,
                       cnt, sec_base, offv, n_needed, comp_xyz, dmin_g, buf,
                       points, comp_idx, s_total, out, &sync_ctr[1]);
}

// Round 13
// 396.311 us; speedup vs baseline: 1.1762x; 1.1142x over previous
//
#include <hip/hip_runtime.h>
#include <cmath>
#include <cstdint>

#pragma clang fp contract(off)

#define B_ 2
#define N_ 65536
#define M_ 128
#define K_ 2048
#define S_ 6
#define NBLK 256          /* classify/compact blocks per batch */
#define CT 256            /* classify/compact threads per block */
#define FPS_T 512         /* 8 waves: 2 waves/SIMD */
#define NW 8              /* FPS_T / 64 waves */
#define RMAX 8            /* per-thread point slots */
#define CAP (FPS_T * RMAX)  /* 4096 points max for register fast path */

#define PI_F 3.14159265358979323846f
#define SS_F 1.0471975511965976f   /* (float)(2.0*pi/6) */

// Wave-wide max of 64-bit keys via DPP (VALU latency, not DS latency).
// Lane 63 holds the result. Identity: key==0 (bound_ctrl zero-fill loses).
__device__ __forceinline__ unsigned long long wave_max_u64_dpp(unsigned long long key) {
#define DPP_STEP(CTRL)                                                          \
    {                                                                           \
        unsigned lo = (unsigned)key, hi = (unsigned)(key >> 32);                \
        unsigned olo = (unsigned)__builtin_amdgcn_update_dpp(0, (int)lo, CTRL, 0xf, 0xf, true); \
        unsigned ohi = (unsigned)__builtin_amdgcn_update_dpp(0, (int)hi, CTRL, 0xf, 0xf, true); \
        unsigned long long o = ((unsigned long long)ohi << 32) | olo;           \
        if (o > key) key = o;                                                   \
    }
    DPP_STEP(0x111)  /* row_shr:1  */
    DPP_STEP(0x112)  /* row_shr:2  */
    DPP_STEP(0x114)  /* row_shr:4  */
    DPP_STEP(0x118)  /* row_shr:8  */
    DPP_STEP(0x142)  /* row_bcast:15 */
    DPP_STEP(0x143)  /* row_bcast:31 */
#undef DPP_STEP
    return key;
}

// ------------------------------------------------------------ classify ----
__global__ __launch_bounds__(CT)
void k_classify(const float* __restrict__ points, const float* __restrict__ rois,
                int* __restrict__ sec_id, int* __restrict__ blkcnt,
                int* __restrict__ done_ctr) {
    __shared__ float4 sroi[M_];
    __shared__ int lc[8];
    int blk = blockIdx.x;
    int gid = blk * CT + threadIdx.x;
    int b = gid >> 16;                       // N_ = 65536
    if (blk == 0 && threadIdx.x == 0) *done_ctr = 0;   // reset fps+out fusion ctr
    if (threadIdx.x < M_) {
        const float* r = rois + ((size_t)b * M_ + threadIdx.x) * 7;
        float cz = r[2] + r[5] * 0.5f;       // geometric center
        float hx = r[3] * 0.5f, hy = r[4] * 0.5f, hz = r[5] * 0.5f;
        sroi[threadIdx.x] = make_float4(r[0], r[1], cz, sqrtf((hx*hx + hy*hy) + hz*hz));
    }
    if (threadIdx.x < 8) lc[threadIdx.x] = 0;
    __syncthreads();

    const float* p = points + (size_t)gid * 3;
    float px = p[0], py = p[1], pz = p[2];
    float best = 1e30f; int bi = 0;
    for (int m = 0; m < M_; m++) {
        float4 c = sroi[m];
        float dx = px - c.x, dy = py - c.y, dz = pz - c.z;
        float d = sqrtf((dx*dx + dy*dy) + dz*dz);
        if (d < best) { best = d; bi = m; }  // strict < : first argmin
    }
    bool valid = best < (sroi[bi].w + 1.6f);

    float a = atan2f(py, px) + PI_F;
    float fs = floorf(a / SS_F);
    fs = fminf(fmaxf(fs, 0.0f), 6.0f);
    int sec = (int)fs;

    sec_id[gid] = valid ? sec : -1;
    if (valid) atomicAdd(&lc[sec], 1);
    __syncthreads();
    if (threadIdx.x < 8) blkcnt[blk * 8 + threadIdx.x] = lc[threadIdx.x];
}

// ----------------------------------------------- compact (+inline plan) ----
// k_plan folded in (verified r9/r10: non-fps 103->68us): each block stages
// its batch's blkcnt (8KB) to LDS, redundantly computes its own block
// prefix + sector totals/bases; block j==0 writes the plan outputs (EXACT
// original formulas incl. f32 ceilf) for k_fps.
__global__ __launch_bounds__(CT)
void k_compact(const float* __restrict__ points, const int* __restrict__ sec_id,
               const int* __restrict__ blkcnt,
               int* __restrict__ cnt, int* __restrict__ offv,
               int* __restrict__ n_needed, int* __restrict__ sec_base_g,
               int* __restrict__ s_total,
               int* __restrict__ comp_idx, float4* __restrict__ comp_xyz) {
    __shared__ int scnt_lds[NBLK][8];        // 8KB: batch-b blkcnt mirror
    __shared__ int sbase[6], blkb[6], stot[8];
    __shared__ int lc[4 * 6];
    int blk = blockIdx.x;
    int b = blk >> 8, j = blk & 255;          // NBLK = 256 blocks per batch
    int tid = threadIdx.x, lane = tid & 63, wid = tid >> 6;

    {   // stage: 256 threads x one 32B row
        const int4* src = (const int4*)(blkcnt + (size_t)(b * NBLK + tid) * 8);
        int4 r0 = src[0], r1 = src[1];
        *(int4*)&scnt_lds[tid][0] = r0;
        *(int4*)&scnt_lds[tid][4] = r1;
    }
    __syncthreads();
    if (tid < 7) {                            // per-sector prefix + total
        int run = 0, pref = 0;
        for (int j2 = 0; j2 < NBLK; j2++) {
            if (j2 == j) pref = run;
            run += scnt_lds[j2][tid];
        }
        stot[tid] = run;
        if (tid < 6) blkb[tid] = pref;
    }
    __syncthreads();
    if (tid == 0) {                           // sector bases from totals
        int sb = 0;
        for (int s = 0; s < 6; s++) { sbase[s] = sb; sb += stot[s]; }
    }
    if (j == 0 && tid == 64) {                // plan outputs (original formulas)
        int total = 0;
        for (int s = 0; s < 7; s++) total += stot[s];
        if (total < 1) total = 1;
        int sb = 0, snk = 0;
        for (int s = 0; s < 6; s++) {
            int cs = stot[s];
            int nk = (int)ceilf((float)cs * 2048.0f / (float)total);  // f32 semantics
            if (nk > cs) nk = cs;
            offv[b * 6 + s] = snk;
            int need = 0;
            if (snk < K_) { need = K_ - snk; if (need > nk) need = nk; }
            n_needed[b * 6 + s] = need;
            sec_base_g[b * 6 + s] = sb;
            cnt[b * 8 + s] = cs;
            sb += cs; snk += nk;
        }
        s_total[b] = (snk < 1) ? 1 : snk;
    }

    int gid = blk * CT + tid;
    int sec = sec_id[gid];
    unsigned long long mymask = 0;
    for (int s = 0; s < 6; s++) {
        unsigned long long m = __ballot(sec == s);
        if (sec == s) mymask = m;
        if (lane == 0) lc[wid * 6 + s] = __popcll(m);
    }
    __syncthreads();
    if (sec >= 0 && sec < 6) {
        int woff = 0;
        for (int w = 0; w < wid; w++) woff += lc[w * 6 + sec];
        int rank = __popcll(mymask & ((1ull << lane) - 1ull));
        int addr = b * N_ + sbase[sec] + blkb[sec] + woff + rank;
        const float* p = points + (size_t)gid * 3;
        comp_idx[addr] = gid & (N_ - 1);
        comp_xyz[addr] = make_float4(p[0], p[1], p[2], 0.0f);
    }
}

// ------------------------------------------------------ fps (+inline out) ----
// one block (512 thr, 8 waves = 2/SIMD) per (b,s). Pick loop is the EXACT
// round-3 text (verified 322us r3 / 326.8 r10 / 326.3 r11 / 324.4 r12 at
// 68 VGPR). r7/r8/r9 post-mortem: every "instruction-count optimization"
// of this loop dropped VGPR 68->52 and REGRESSED 15-30% at equal
// VALU-cycles — the allocator packs the loop tighter and serializes the
// t[4] ILP chains. DO NOT TOUCH THE LOOP BODY.
// Fused k_out tail (verified r9-r12): release = threadfence + atomicAdd
// after writeback; last arriver gathers out[]. All blocks reach the counter.
__global__ __launch_bounds__(FPS_T, 2)
void k_fps(const int* __restrict__ cnt, const int* __restrict__ sec_base,
           const int* __restrict__ offv, const int* __restrict__ n_needed,
           const float4* __restrict__ comp_xyz,
           float* __restrict__ dmin_g, int* __restrict__ buf,
           const float* __restrict__ points, const int* __restrict__ comp_idx,
           const int* __restrict__ s_total, float* __restrict__ out,
           int* __restrict__ done_ctr) {
    __shared__ float4 sxyz[CAP];
    __shared__ int pick_lds[K_];
    __shared__ unsigned long long skey[2][NW];
    __shared__ int is_last;
    int b = blockIdx.x / S_, s = blockIdx.x % S_;
    int need = n_needed[b * 6 + s];
    int cs = cnt[b * 8 + s];
    int base = b * N_ + sec_base[b * 6 + s];
    const float4* cxyz = comp_xyz + base;
    int off = b * K_ + offv[b * 6 + s];
    int tid = threadIdx.x, lane = tid & 63, wid = tid >> 6;

    if (need > 0 && cs <= CAP) {
        // ---- fast path: points + dmin in registers, xyz mirror in LDS ----
        float px[RMAX], py[RMAX], pz[RMAX], dmv[RMAX];
        #pragma unroll
        for (int r = 0; r < RMAX; r++) {
            if (r * FPS_T < cs) {
                int i = tid + r * FPS_T;
                if (i < cs) {
                    float4 q = cxyz[i];
                    sxyz[i] = q;
                    px[r] = q.x; py[r] = q.y; pz[r] = q.z;
                    dmv[r] = 1e10f;
                }
            }
        }
        if (tid == 0) pick_lds[0] = 0;       // first pick = first point
        __syncthreads();
        float4 l4 = sxyz[0];
        float lx = l4.x, ly = l4.y, lz = l4.z;

        #pragma unroll 1
        for (int k = 1; k < need; k++) {
            unsigned long long t[4] = {0ull, 0ull, 0ull, 0ull};
            #pragma unroll
            for (int r = 0; r < RMAX; r++) {
                if (r * FPS_T < cs) {        // wave-uniform
                    int i = tid + r * FPS_T;
                    if (i < cs) {
                        float dx = px[r] - lx, dy = py[r] - ly, dz = pz[r] - lz;
                        float d = (dx*dx + dy*dy) + dz*dz;    // contract off
                        float nd = fminf(dmv[r], d);
                        dmv[r] = nd;
                        unsigned long long kk =
                            ((unsigned long long)__float_as_uint(nd) << 32) | (unsigned)(~(unsigned)i);
                        if (kk > t[r & 3]) t[r & 3] = kk;     // 4 parallel chains
                    }
                }
            }
            unsigned long long ta = (t[1] > t[0]) ? t[1] : t[0];
            unsigned long long tb = (t[3] > t[2]) ? t[3] : t[2];
            unsigned long long key = (tb > ta) ? tb : ta;
            key = wave_max_u64_dpp(key);
            int par = k & 1;
            if (lane == 63) skey[par][wid] = key;
            __syncthreads();
            unsigned long long q0 = skey[par][0], q1 = skey[par][1];
            unsigned long long q2 = skey[par][2], q3 = skey[par][3];
            unsigned long long q4 = skey[par][4], q5 = skey[par][5];
            unsigned long long q6 = skey[par][6], q7 = skey[par][7];
            q0 = (q1 > q0) ? q1 : q0;
            q2 = (q3 > q2) ? q3 : q2;
            q4 = (q5 > q4) ? q5 : q4;
            q6 = (q7 > q6) ? q7 : q6;
            q0 = (q2 > q0) ? q2 : q0;
            q4 = (q6 > q4) ? q6 : q4;
            unsigned long long bk = (q4 > q0) ? q4 : q0;
            int bix = (int)(~(unsigned)(bk & 0xFFFFFFFFull));
            if (tid == 0) pick_lds[k] = bix;                  // LDS, not global
            float4 n4 = sxyz[bix];                            // LDS broadcast
            lx = n4.x; ly = n4.y; lz = n4.z;
        }
        __syncthreads();
        // coalesced writeback of all picks
        #pragma unroll 1
        for (int i = tid; i < need; i += FPS_T)
            buf[off + i] = base + pick_lds[i];
    } else if (need > 0) {
        // ---- fallback: dmin in global (not taken for this data: cs<=CAP) ----
        float* dm = dmin_g + base;
        if (tid == 0) pick_lds[0] = 0;
        __syncthreads();
        float4 f0 = cxyz[0];
        float lx = f0.x, ly = f0.y, lz = f0.z;
        #pragma unroll 1
        for (int k = 1; k < need; k++) {
            unsigned long long key = 0;
            #pragma unroll 1
            for (int i = tid; i < cs; i += FPS_T) {
                float4 q = cxyz[i];
                float dx = q.x - lx, dy = q.y - ly, dz = q.z - lz;
                float d = (dx*dx + dy*dy) + dz*dz;
                float prev = (k == 1) ? 1e10f : dm[i];
                float nd = fminf(prev, d);
                dm[i] = nd;
                unsigned long long kk =
                    ((unsigned long long)__float_as_uint(nd) << 32) | (unsigned)(~(unsigned)i);
                if (kk > key) key = kk;
            }
            key = wave_max_u64_dpp(key);
            int par = k & 1;
            if (lane == 63) skey[par][wid] = key;
            __syncthreads();
            unsigned long long q0 = skey[par][0], q1 = skey[par][1];
            unsigned long long q2 = skey[par][2], q3 = skey[par][3];
            unsigned long long q4 = skey[par][4], q5 = skey[par][5];
            unsigned long long q6 = skey[par][6], q7 = skey[par][7];
            q0 = (q1 > q0) ? q1 : q0;
            q2 = (q3 > q2) ? q3 : q2;
            q4 = (q5 > q4) ? q5 : q4;
            q6 = (q7 > q6) ? q7 : q6;
            q0 = (q2 > q0) ? q2 : q0;
            q4 = (q6 > q4) ? q6 : q4;
            unsigned long long bk = (q4 > q0) ? q4 : q0;
            int bix = (int)(~(unsigned)(bk & 0xFFFFFFFFull));
            if (tid == 0) pick_lds[k] = bix;
            float4 n4 = cxyz[bix];                            // rare path
            lx = n4.x; ly = n4.y; lz = n4.z;
        }
        __syncthreads();
        #pragma unroll 1
        for (int i = tid; i < need; i += FPS_T)
            buf[off + i] = base + pick_lds[i];
    }

    // ---- last-block inline k_out (all 12 blocks arrive here) ----
    __syncthreads();                          // writeback done (block-local)
    if (tid == 0) {
        __threadfence();                      // release buf writes
        int old = atomicAdd(done_ctr, 1);     // device-scope
        is_last = (old == B_ * S_ - 1) ? 1 : 0;
    }
    __syncthreads();
    if (is_last) {
        __threadfence();                      // acquire other blocks' buf
        #pragma unroll 1
        for (int i = tid; i < B_ * K_; i += FPS_T) {
            int b2 = i / K_, j2 = i - b2 * K_;
            int st = s_total[b2];
            int g = buf[b2 * K_ + (j2 % st)]; // compacted global slot
            int idx = comp_idx[g];            // original point index
            const float* p = points + ((size_t)b2 * N_ + idx) * 3;
            float* o = out + (size_t)i * 3;
            o[0] = p[0]; o[1] = p[1]; o[2] = p[2];
        }
    }
}

// -------------------------------------------------------------- launch ----
extern "C" void kernel_launch(void* const* d_in, const int* in_sizes, int n_in,
                              void* d_out, int out_size, void* d_ws, size_t ws_size,
                              hipStream_t stream) {
    const float* points = (const float*)d_in[0];   // [B,N,3]
    const float* rois   = (const float*)d_in[1];   // [B,M,7]
    float* out = (float*)d_out;                    // [B,K,3]

    char* w = (char*)d_ws;
    auto carve = [&](size_t bytes) -> char* {
        char* p = w; w += (bytes + 255) & ~(size_t)255; return p;
    };
    int*    sec_id   = (int*)   carve((size_t)B_ * N_ * sizeof(int));
    int*    blkcnt   = (int*)   carve((size_t)B_ * NBLK * 8 * sizeof(int));
    int*    cnt      = (int*)   carve((size_t)B_ * 8 * sizeof(int));
    int*    offv     = (int*)   carve((size_t)B_ * 6 * sizeof(int));
    int*    n_needed = (int*)   carve((size_t)B_ * 6 * sizeof(int));
    int*    sec_base = (int*)   carve((size_t)B_ * 6 * sizeof(int));
    int*    s_total  = (int*)   carve((size_t)B_ * sizeof(int));
    int*    buf      = (int*)   carve((size_t)B_ * K_ * sizeof(int));
    int*    comp_idx = (int*)   carve((size_t)B_ * N_ * sizeof(int));
    float4* comp_xyz = (float4*)carve((size_t)B_ * N_ * sizeof(float4));
    float*  dmin_g   = (float*) carve((size_t)B_ * N_ * sizeof(float));
    int*    done_ctr = (int*)   carve(sizeof(int));

    hipLaunchKernelGGL(k_classify, dim3(B_ * NBLK), dim3(CT), 0, stream,
                       points, rois, sec_id, blkcnt, done_ctr);
    hipLaunchKernelGGL(k_compact, dim3(B_ * NBLK), dim3(CT), 0, stream,
                       points, sec_id, blkcnt, cnt, offv, n_needed, sec_base,
                       s_total, comp_idx, comp_xyz);
    hipLaunchKernelGGL(k_fps, dim3(B_ * S_), dim3(FPS_T), 0, stream,
                       cnt, sec_base, offv, n_needed, comp_xyz, dmin_g, buf,
                       points, comp_idx, s_total, out, done_ctr);
}